// Round 3
// baseline (113.526 us; speedup 1.0000x reference)
//
#include <hip/hip_runtime.h>
#include <math.h>

// Problem constants (match reference)
#define NXC 1024
#define NYC 1024
#define DC  128
#define NCM1 4
#define NBLK 256   // 16x16 tiles of 64x64 -> must equal #CUs for the spin barrier

// ws float offsets
#define WS_ROWPM 0        // 1024*16  per-tile row partial max
#define WS_ROWPL 16384    // 1024*16  per-tile row partial sumexp
#define WS_COLPM 32768    // 1024*16
#define WS_COLPL 49152    // 1024*16
#define WS_ACC   65536    // 2 floats (S0, S1)
#define WS_CNT   65544    // 2 ints (barrier counters) -- int offset into ws

__global__ void init_kernel(float* ws) {
    if (threadIdx.x == 0) {
        ws[WS_ACC]     = 0.f;
        ws[WS_ACC + 1] = 0.f;
        ((int*)ws)[WS_CNT]     = 0;
        ((int*)ws)[WS_CNT + 1] = 0;
    }
}

// -------------------------------------------------------------------------
// Single persistent kernel. 256 blocks (1 per CU) x 256 threads.
// Block = 64x64 tile of s, 4x4 micro-tile per thread held in registers the
// whole time. Grid barriers via device-scope atomics (all blocks co-resident:
// grid == #CUs, 64KB LDS, <=1 block/CU needed).
// -------------------------------------------------------------------------
__global__ __launch_bounds__(256) void fused_kernel(
    const float* __restrict__ zx, const float* __restrict__ zy,
    const float* __restrict__ theta, const float* __restrict__ beta,
    float* __restrict__ ws, float* __restrict__ out)
{
    __shared__ __align__(16) float xs[64 * 128];
    __shared__ __align__(16) float ys[64 * 128];
    __shared__ float cpm[16][64];   // per-ty col partial max
    __shared__ float cpl[16][64];   // per-ty col partial sumexp
    __shared__ float rm_s[64], rl_s[64];  // combined row max / inv-sumexp for this tile's rows
    __shared__ float cm_s[64], cl_s[64];  // combined col max / inv-sumexp for this tile's cols
    __shared__ float red0[4], red1[4];

    float* rowp_m = ws + WS_ROWPM;
    float* rowp_l = ws + WS_ROWPL;
    float* colp_m = ws + WS_COLPM;
    float* colp_l = ws + WS_COLPL;
    float* acc    = ws + WS_ACC;
    int*   cnt    = (int*)ws + WS_CNT;

    const int t  = threadIdx.x;
    const int bx = blockIdx.x & 15;   // col-tile index
    const int by = blockIdx.x >> 4;   // row-tile index
    const int x0 = by * 64;
    const int y0 = bx * 64;

    // ---- Phase 1a: stage 64x128 of zx and zy into LDS (XOR-swizzled) ----
    #pragma unroll
    for (int k = 0; k < 8; ++k) {
        int idx = t + k * 256;
        int r   = idx >> 5;
        int c4  = idx & 31;
        int dsw = (c4 * 4) ^ (4 * ((r >> 2) & 7));
        float4 xv = ((const float4*)(zx + (size_t)(x0 + r) * DC))[c4];
        float4 yv = ((const float4*)(zy + (size_t)(y0 + r) * DC))[c4];
        *(float4*)(xs + r * 128 + dsw) = xv;
        *(float4*)(ys + r * 128 + dsw) = yv;
    }
    __syncthreads();

    const int tx = t & 15;
    const int ty = t >> 4;
    const int xsw = 4 * (ty & 7);
    const int ysw = 4 * (tx & 7);

    // ---- Phase 1b: 4x4 micro-tile L1 distances ----
    float sv[4][4];
    #pragma unroll
    for (int i = 0; i < 4; ++i)
        #pragma unroll
        for (int j = 0; j < 4; ++j) sv[i][j] = 0.f;

    const float* xb = xs + (4 * ty) * 128;
    const float* yb = ys + (4 * tx) * 128;

    #pragma unroll 4
    for (int d = 0; d < DC; d += 4) {
        float4 xv[4], yv[4];
        #pragma unroll
        for (int i = 0; i < 4; ++i) xv[i] = *(const float4*)(xb + i * 128 + (d ^ xsw));
        #pragma unroll
        for (int j = 0; j < 4; ++j) yv[j] = *(const float4*)(yb + j * 128 + (d ^ ysw));
        #pragma unroll
        for (int i = 0; i < 4; ++i)
            #pragma unroll
            for (int j = 0; j < 4; ++j) {
                sv[i][j] += fabsf(xv[i].x - yv[j].x) + fabsf(xv[i].y - yv[j].y)
                          + fabsf(xv[i].z - yv[j].z) + fabsf(xv[i].w - yv[j].w);
            }
    }
    // negate: s = -sum|.|
    #pragma unroll
    for (int i = 0; i < 4; ++i)
        #pragma unroll
        for (int j = 0; j < 4; ++j) sv[i][j] = -sv[i][j];

    // ---- Phase 1c: per-tile ROW partials (m,l over the tile's 64 cols) ----
    #pragma unroll
    for (int i = 0; i < 4; ++i) {
        float m = fmaxf(fmaxf(sv[i][0], sv[i][1]), fmaxf(sv[i][2], sv[i][3]));
        float l = __expf(sv[i][0] - m) + __expf(sv[i][1] - m)
                + __expf(sv[i][2] - m) + __expf(sv[i][3] - m);
        // merge across the 16 lanes sharing this row (same ty, tx=0..15; in-wave)
        #pragma unroll
        for (int off = 1; off < 16; off <<= 1) {
            float mo = __shfl_xor(m, off, 64);
            float lo = __shfl_xor(l, off, 64);
            float nm = fmaxf(m, mo);
            l = l * __expf(m - nm) + lo * __expf(mo - nm);
            m = nm;
        }
        if (tx == 0) {
            rowp_m[(size_t)(x0 + 4 * ty + i) * 16 + bx] = m;
            rowp_l[(size_t)(x0 + 4 * ty + i) * 16 + bx] = l;
        }
    }

    // ---- Phase 1d: per-tile COL partials (m,l over the tile's 64 rows) ----
    #pragma unroll
    for (int j = 0; j < 4; ++j) {
        float m = fmaxf(fmaxf(sv[0][j], sv[1][j]), fmaxf(sv[2][j], sv[3][j]));
        float l = __expf(sv[0][j] - m) + __expf(sv[1][j] - m)
                + __expf(sv[2][j] - m) + __expf(sv[3][j] - m);
        cpm[ty][4 * tx + j] = m;
        cpl[ty][4 * tx + j] = l;
    }
    __syncthreads();
    if (t < 64) {
        float m = cpm[0][t], l = cpl[0][t];
        #pragma unroll
        for (int k = 1; k < 16; ++k) {
            float mo = cpm[k][t], lo = cpl[k][t];
            float nm = fmaxf(m, mo);
            l = l * __expf(m - nm) + lo * __expf(mo - nm);
            m = nm;
        }
        colp_m[(size_t)(y0 + t) * 16 + by] = m;
        colp_l[(size_t)(y0 + t) * 16 + by] = l;
    }

    // ---- Grid barrier 1 ----
    __syncthreads();
    if (t == 0) {
        __threadfence();
        __hip_atomic_fetch_add(&cnt[0], 1, __ATOMIC_ACQ_REL, __HIP_MEMORY_SCOPE_AGENT);
        while (__hip_atomic_load(&cnt[0], __ATOMIC_ACQUIRE, __HIP_MEMORY_SCOPE_AGENT) < NBLK)
            __builtin_amdgcn_s_sleep(8);
        __threadfence();
    }
    __syncthreads();

    // ---- Phase 2: combine the 16 partials for this tile's rows and cols ----
    if (t < 64) {
        const size_t i = (size_t)(x0 + t) * 16;
        float m = rowp_m[i], l = rowp_l[i];
        #pragma unroll
        for (int k = 1; k < 16; ++k) {
            float mo = rowp_m[i + k], lo = rowp_l[i + k];
            float nm = fmaxf(m, mo);
            l = l * __expf(m - nm) + lo * __expf(mo - nm);
            m = nm;
        }
        rm_s[t] = m;
        rl_s[t] = 1.f / l;
    } else if (t < 128) {
        const size_t c = (size_t)(y0 + (t - 64)) * 16;
        float m = colp_m[c], l = colp_l[c];
        #pragma unroll
        for (int k = 1; k < 16; ++k) {
            float mo = colp_m[c + k], lo = colp_l[c + k];
            float nm = fmaxf(m, mo);
            l = l * __expf(m - nm) + lo * __expf(mo - nm);
            m = nm;
        }
        cm_s[t - 64] = m;
        cl_s[t - 64] = 1.f / l;
    }
    __syncthreads();

    // ---- Phase 3: weighted reduction from registers ----
    float S0 = 0.f, S1 = 0.f;
    #pragma unroll
    for (int i = 0; i < 4; ++i) {
        const float rm = rm_s[4 * ty + i];
        const float rl = rl_s[4 * ty + i];
        #pragma unroll
        for (int j = 0; j < 4; ++j) {
            const float cm = cm_s[4 * tx + j];
            const float cl = cl_s[4 * tx + j];
            float s = sv[i][j];
            float a = __expf(s - rm) * rl;
            float b = __expf(s - cm) * cl;
            float w = a + b - a * b;
            S0 += w;
            S1 += w * s;
        }
    }
    #pragma unroll
    for (int off = 32; off; off >>= 1) {
        S0 += __shfl_xor(S0, off, 64);
        S1 += __shfl_xor(S1, off, 64);
    }
    {
        const int wave = t >> 6, lane = t & 63;
        if (lane == 0) { red0[wave] = S0; red1[wave] = S1; }
    }
    __syncthreads();
    if (t == 0) {
        float t0 = red0[0] + red0[1] + red0[2] + red0[3];
        float t1 = red1[0] + red1[1] + red1[2] + red1[3];
        atomicAdd(&acc[0], t0);
        atomicAdd(&acc[1], t1);
    }

    // ---- Grid barrier 2 (only block 0 waits) + finalize ----
    __syncthreads();
    if (t == 0) {
        __threadfence();
        __hip_atomic_fetch_add(&cnt[1], 1, __ATOMIC_ACQ_REL, __HIP_MEMORY_SCOPE_AGENT);
    }
    if (blockIdx.x == 0) {
        if (t == 0) {
            while (__hip_atomic_load(&cnt[1], __ATOMIC_ACQUIRE, __HIP_MEMORY_SCOPE_AGENT) < NBLK)
                __builtin_amdgcn_s_sleep(8);
            __threadfence();
        }
        __syncthreads();
        if (t < NCM1) {
            float t0 = __hip_atomic_load(&acc[0], __ATOMIC_ACQUIRE, __HIP_MEMORY_SCOPE_AGENT);
            float t1 = __hip_atomic_load(&acc[1], __ATOMIC_ACQUIRE, __HIP_MEMORY_SCOPE_AGENT);
            float c = t1 / t0;
            out[t] = c * theta[t] + beta[t];
        }
    }
}

// -------------------------------------------------------------------------
extern "C" void kernel_launch(void* const* d_in, const int* in_sizes, int n_in,
                              void* d_out, int out_size, void* d_ws, size_t ws_size,
                              hipStream_t stream)
{
    const float* zx    = (const float*)d_in[0];
    const float* zy    = (const float*)d_in[1];
    const float* theta = (const float*)d_in[2];
    const float* beta  = (const float*)d_in[3];
    float* out = (float*)d_out;
    float* ws  = (float*)d_ws;

    init_kernel<<<1, 64, 0, stream>>>(ws);
    fused_kernel<<<NBLK, 256, 0, stream>>>(zx, zy, theta, beta, ws, out);
}